// Round 5
// baseline (25.264 us; speedup 1.0000x reference)
//
#include <hip/hip_runtime.h>

// RadiusGraphLayer: out[0..N^2) = dist, out[N^2..2N^2) = mask (f32 0/1).
// N=4096, 8 graphs x 512 atoms (batch = arange//512 by construction).
// Write-BW-bound: 134.2 MB mandatory output. Fill parity ~19.7 us @ 6.8 TB/s.
//
// Lessons: R2 nontemporal stores bypass L2 write-combining (-5us). R3 dual
// 8MB-strided streams 64MB apart: 27.7. R4 flat 1-store/thread: 24.2 (32k WG
// dispatch + prologue per store). R5: exact fillBufferAligned clone — 2048
// blocks x 256 thr x 16 grid-stride iters, ONE ascending flat stream over the
// concatenated output, compute inlined on the 1/8 wave-uniform diag iters.

#define NATOMS 4096
#define HALF_QUADS (NATOMS * NATOMS / 4)   // 4,194,304 = 2^22 quads per half
#define NTHREADS (2048 * 256)              // 524,288 -> 16 iters, stride 8 MB

typedef float f4 __attribute__((ext_vector_type(4)));

__global__ __launch_bounds__(256) void radius_graph_kernel(
    const float* __restrict__ pos,
    float*       __restrict__ out)
{
    const int tid = blockIdx.x * 256 + threadIdx.x;   // [0, 524288)

    #pragma unroll
    for (int it = 0; it < 16; ++it) {
        const int f  = tid + it * NTHREADS;           // flat quad idx, ascending
        const int tq = f & (HALF_QUADS - 1);          // quad within half
        const int i  = tq >> 10;                      // row 0..4095
        const int jb = (tq & 1023) >> 7;              // col graph-block 0..7

        f4 v = (f4)0.0f;

        if ((i >> 9) == jb) {                         // same-graph block (1/8)
            const bool is_mask = f >= HALF_QUADS;
            const int  j0 = (tq & 1023) << 2;
            // 12 contiguous floats, 48B-aligned -> three dwordx4 (L2-hot, 48KB)
            const f4* pj = (const f4*)(pos + j0 * 3);
            const f4 p0 = pj[0], p1 = pj[1], p2 = pj[2];
            const float xj[4] = {p0.x, p0.w, p1.z, p2.y};
            const float yj[4] = {p0.y, p1.x, p1.w, p2.z};
            const float zj[4] = {p0.z, p1.y, p2.x, p2.w};
            const float xi = pos[i * 3 + 0];
            const float yi = pos[i * 3 + 1];
            const float zi = pos[i * 3 + 2];

            #pragma unroll
            for (int k = 0; k < 4; ++k) {
                // Un-contracted f32: match numpy bit-for-bit on d2<=25 boundary.
                const float dx = __fsub_rn(xi, xj[k]);
                const float dy = __fsub_rn(yi, yj[k]);
                const float dz = __fsub_rn(zi, zj[k]);
                const float d2 = __fadd_rn(
                    __fadd_rn(__fmul_rn(dx, dx), __fmul_rn(dy, dy)),
                    __fmul_rn(dz, dz));
                const bool me = (i != (j0 + k)) && (d2 <= 25.0f);
                v[k] = me ? (is_mask ? 1.0f : sqrtf(d2)) : 0.0f;
            }
        }

        *(f4*)(out + (long long)f * 4) = v;
    }
}

extern "C" void kernel_launch(void* const* d_in, const int* in_sizes, int n_in,
                              void* d_out, int out_size, void* d_ws, size_t ws_size,
                              hipStream_t stream)
{
    const float* pos = (const float*)d_in[0];
    radius_graph_kernel<<<2048, 256, 0, stream>>>(pos, (float*)d_out);
}